// Round 10
// baseline (251.430 us; speedup 1.0000x reference)
//
#include <hip/hip_runtime.h>
#include <math.h>

#define DIMN 1536
#define NHEAD 12
#define HDIM 128
#define SLEN 2048
#define EPSV 1e-6f

typedef __attribute__((ext_vector_type(8))) short short8;
typedef __attribute__((ext_vector_type(4))) short short4v;
typedef __attribute__((ext_vector_type(4))) float f32x4;

typedef __attribute__((address_space(1))) const void gvoid_t;
typedef __attribute__((address_space(3))) void lvoid_t;

__device__ __forceinline__ void gload_lds16(const void* g, void* l) {
    __builtin_amdgcn_global_load_lds((gvoid_t*)g, (lvoid_t*)l, 16, 0, 0);
}

__device__ inline short to_bf16(float f) {
    union { float f; unsigned u; } v; v.f = f;
    unsigned r = (v.u + 0x7FFFu + ((v.u >> 16) & 1u)) >> 16;
    return (short)r;
}
__device__ inline float bf_to_f(short h) {
    union { unsigned u; float f; } v;
    v.u = ((unsigned)(unsigned short)h) << 16;
    return v.f;
}

// 8-chunk XOR swizzle for the GEMM LDS tiles.
__device__ __forceinline__ int swz8(int row, int c) {
    return c ^ (row & 7);
}

// ---------------------------------------------------------------------------
// Cast 5 fp32 tensors to bf16 (x + 4 weights), one launch.
// ---------------------------------------------------------------------------
__global__ __launch_bounds__(256)
void cast5(const float* s0, const float* s1, const float* s2,
           const float* s3, const float* s4,
           short* d0, short* d1, short* d2, short* d3, short* d4,
           int n0, int nw)
{
    const float* s; short* d; int n;
    switch (blockIdx.y) {
        case 0: s = s0; d = d0; n = n0; break;
        case 1: s = s1; d = d1; n = nw; break;
        case 2: s = s2; d = d2; n = nw; break;
        case 3: s = s3; d = d3; n = nw; break;
        default: s = s4; d = d4; n = nw; break;
    }
    int idx = (blockIdx.x * 256 + threadIdx.x) * 8;
    if (idx >= n) return;
    float4 a = *(const float4*)(s + idx);
    float4 b = *(const float4*)(s + idx + 4);
    short8 r;
    r[0] = to_bf16(a.x); r[1] = to_bf16(a.y); r[2] = to_bf16(a.z); r[3] = to_bf16(a.w);
    r[4] = to_bf16(b.x); r[5] = to_bf16(b.y); r[6] = to_bf16(b.z); r[7] = to_bf16(b.w);
    *(short8*)(d + idx) = r;
}

// ---------------------------------------------------------------------------
// BM=64 x BN=128 x BK=64 MFMA GEMM core, two-barrier single-buffer.
// (R7 structure, unchanged — grid-balanced, cross-block TLP hides staging.)
// ---------------------------------------------------------------------------
__device__ __forceinline__ void gemm_mainloop(const short* __restrict__ A,
    const short* __restrict__ W, int m0, int n0, int K,
    short* As, short* Bs, f32x4 (&acc)[2][4])
{
    const int tid = threadIdx.x;
    const int wave = tid >> 6, lane = tid & 63;
    const int quad = lane >> 4, col = lane & 15;
    const int wm = wave >> 1, wn = wave & 1;
    const int sr = tid >> 3;     // 0..31
    const int sc = tid & 7;

    for (int kt = 0; kt < K; kt += 64) {
        __syncthreads();
        #pragma unroll
        for (int i = 0; i < 2; ++i) {
            const int row = i * 32 + sr;
            const int c = swz8(row, sc);
            gload_lds16(A + (size_t)(m0 + row) * K + kt + c * 8, As + i * 2048 + tid * 8);
        }
        #pragma unroll
        for (int i = 0; i < 4; ++i) {
            const int row = i * 32 + sr;
            const int c = swz8(row, sc);
            gload_lds16(W + (size_t)(n0 + row) * K + kt + c * 8, Bs + i * 2048 + tid * 8);
        }
        __syncthreads();

        #pragma unroll
        for (int kb = 0; kb < 2; ++kb) {
            short8 af[2], bf[4];
            #pragma unroll
            for (int mt = 0; mt < 2; ++mt) {
                const int row = wm * 32 + mt * 16 + col;
                af[mt] = *(const short8*)&As[row * 64 + swz8(row, kb * 4 + quad) * 8];
            }
            #pragma unroll
            for (int nt = 0; nt < 4; ++nt) {
                const int row = wn * 64 + nt * 16 + col;
                bf[nt] = *(const short8*)&Bs[row * 64 + swz8(row, kb * 4 + quad) * 8];
            }
            #pragma unroll
            for (int mt = 0; mt < 2; ++mt)
                #pragma unroll
                for (int nt = 0; nt < 4; ++nt)
                    acc[mt][nt] = __builtin_amdgcn_mfma_f32_16x16x32_bf16(
                        af[mt], bf[nt], acc[mt][nt], 0, 0, 0);
        }
    }
}

// ---------------------------------------------------------------------------
// Fused QKV GEMM, 64x128 tiles; sel==2 (V) writes fragment-swizzled Vp.
// Vp chunks are 32-key-step-major: chunk = (head*64 + step)*8 + dt; each
// step's V tile is 8 KB contiguous and fragment-ready for attn.
// ---------------------------------------------------------------------------
__global__ __launch_bounds__(256)
void gemm_qkv(const short* __restrict__ A,
              const short* __restrict__ W0, const short* __restrict__ W1,
              const short* __restrict__ W2,
              const float* __restrict__ b0, const float* __restrict__ b1,
              const float* __restrict__ b2,
              short* __restrict__ Y0, short* __restrict__ Y1,
              short* __restrict__ Vp)
{
    __shared__ __attribute__((aligned(16))) short As[64 * 64];
    __shared__ __attribute__((aligned(16))) short Bs[128 * 64];

    const int sel = blockIdx.x / (DIMN / 128);
    const int nb  = blockIdx.x % (DIMN / 128);
    const short* W    = (sel == 0) ? W0 : (sel == 1) ? W1 : W2;
    const float* bias = (sel == 0) ? b0 : (sel == 1) ? b1 : b2;

    const int tid = threadIdx.x;
    const int wave = tid >> 6, lane = tid & 63;
    const int quad = lane >> 4, col = lane & 15;
    const int wm = wave >> 1, wn = wave & 1;
    const int m0 = blockIdx.y * 64, n0 = nb * 128;

    f32x4 acc[2][4];
    #pragma unroll
    for (int i = 0; i < 2; ++i)
        #pragma unroll
        for (int j = 0; j < 4; ++j)
            #pragma unroll
            for (int r = 0; r < 4; ++r) acc[i][j][r] = 0.f;

    gemm_mainloop(A, W, m0, n0, DIMN, As, Bs, acc);

    if (sel < 2) {
        short* Y = (sel == 0) ? Y0 : Y1;
        #pragma unroll
        for (int mt = 0; mt < 2; ++mt) {
            #pragma unroll
            for (int nt = 0; nt < 4; ++nt) {
                const int n = n0 + wn * 64 + nt * 16 + col;
                const float bb = bias[n];
                #pragma unroll
                for (int r = 0; r < 4; ++r) {
                    const int m = m0 + wm * 32 + mt * 16 + quad * 4 + r;
                    Y[(size_t)m * DIMN + n] = to_bf16(acc[mt][nt][r] + bb);
                }
            }
        }
    } else {
        const int head = nb;
        const int step = blockIdx.y * 2 + wm;      // 32-key step index
        #pragma unroll
        for (int mt = 0; mt < 2; ++mt) {
            #pragma unroll
            for (int nt = 0; nt < 4; ++nt) {
                const int n = n0 + wn * 64 + nt * 16 + col;
                const float bb = bias[n];
                const int dt = wn * 4 + nt;
                const int chunk = (head * 64 + step) * 8 + dt;
                const int off = (mt * 2 + (quad >> 1)) * 128 + col * 8 + (quad & 1) * 4;
                short4v o;
                #pragma unroll
                for (int r = 0; r < 4; ++r) o[r] = to_bf16(acc[mt][nt][r] + bb);
                *(short4v*)(Vp + (size_t)chunk * 512 + off) = o;
            }
        }
    }
}

// ---------------------------------------------------------------------------
// Output-projection GEMM, 64x128 tiles, fp32 out.
// ---------------------------------------------------------------------------
__global__ __launch_bounds__(256)
void gemm_out(const short* __restrict__ A, const short* __restrict__ W,
              const float* __restrict__ bias, float* __restrict__ Yf)
{
    __shared__ __attribute__((aligned(16))) short As[64 * 64];
    __shared__ __attribute__((aligned(16))) short Bs[128 * 64];

    const int tid = threadIdx.x;
    const int wave = tid >> 6, lane = tid & 63;
    const int quad = lane >> 4, col = lane & 15;
    const int wm = wave >> 1, wn = wave & 1;
    const int m0 = blockIdx.y * 64, n0 = blockIdx.x * 128;

    f32x4 acc[2][4];
    #pragma unroll
    for (int i = 0; i < 2; ++i)
        #pragma unroll
        for (int j = 0; j < 4; ++j)
            #pragma unroll
            for (int r = 0; r < 4; ++r) acc[i][j][r] = 0.f;

    gemm_mainloop(A, W, m0, n0, DIMN, As, Bs, acc);

    #pragma unroll
    for (int mt = 0; mt < 2; ++mt) {
        #pragma unroll
        for (int nt = 0; nt < 4; ++nt) {
            const int n = n0 + wn * 64 + nt * 16 + col;
            const float bb = bias[n];
            #pragma unroll
            for (int r = 0; r < 4; ++r) {
                const int m = m0 + wm * 32 + mt * 16 + quad * 4 + r;
                Yf[(size_t)m * DIMN + n] = acc[mt][nt][r] + bb;
            }
        }
    }
}

// ---------------------------------------------------------------------------
// Fused RMSNorm + RoPE for Q (grid.y==0, in-place) and K->Kp (grid.y==1).
// ---------------------------------------------------------------------------
__global__ __launch_bounds__(256)
void rms_rope_qk(short* __restrict__ qbuf, const short* __restrict__ kbuf,
                 short* __restrict__ Kp,
                 const float* __restrict__ gq, const float* __restrict__ gk,
                 const float* __restrict__ freqs, const int* __restrict__ grid_sizes)
{
    const int s = blockIdx.x;
    const int isK = blockIdx.y;
    const int tid = threadIdx.x;
    short* qrow = qbuf + (size_t)s * DIMN;
    const short* row = isK ? (kbuf + (size_t)s * DIMN) : qrow;
    const float* g = isK ? gk : gq;

    float ss = 0.f;
    if (tid < 192) {
        short8 v = *(const short8*)(row + tid * 8);
        #pragma unroll
        for (int j = 0; j < 8; ++j) { float f = bf_to_f(v[j]); ss += f * f; }
    }
    #pragma unroll
    for (int off = 32; off; off >>= 1) ss += __shfl_down(ss, off, 64);

    __shared__ float red[4];
    __shared__ float s_scale;
    if ((tid & 63) == 0) red[tid >> 6] = ss;
    __syncthreads();
    if (tid == 0) {
        float t = red[0] + red[1] + red[2] + red[3];
        float sc = rsqrtf(t / (float)DIMN + EPSV);
        s_scale = isK ? sc : sc * 0.08838834764831845f;
    }
    __syncthreads();
    const float scale = s_scale;

    const int h = grid_sizes[1], w = grid_sizes[2];
    const int fi = s / (h * w);
    const int hi = (s / w) % h;
    const int wi = s % w;

    if (!isK) {
        for (int p = tid; p < NHEAD * 64; p += 256) {
            const int n = p >> 6;
            const int d = p & 63;
            const int idx = (d < 22) ? fi : ((d < 43) ? hi : wi);
            const float ang = freqs[idx * 64 + d];
            float sn, cs;
            __sincosf(ang, &sn, &cs);
            const int base = n * HDIM + 2 * d;
            const float v0 = bf_to_f(qrow[base]) * scale * g[base];
            const float v1 = bf_to_f(qrow[base + 1]) * scale * g[base + 1];
            qrow[base]     = to_bf16(v0 * cs - v1 * sn);
            qrow[base + 1] = to_bf16(v0 * sn + v1 * cs);
        }
    } else if (tid < 192) {
        const int n = tid >> 4;
        const int o = tid & 15;
        short8 outv;
        #pragma unroll
        for (int pp = 0; pp < 4; ++pp) {
            const int pd = o * 4 + pp;
            const int idx = (pd < 22) ? fi : ((pd < 43) ? hi : wi);
            const float ang = freqs[idx * 64 + pd];
            float sn, cs;
            __sincosf(ang, &sn, &cs);
            const int base = n * HDIM + 2 * pd;
            const float v0 = bf_to_f(row[base]) * scale * g[base];
            const float v1 = bf_to_f(row[base + 1]) * scale * g[base + 1];
            outv[pp * 2]     = to_bf16(v0 * cs - v1 * sn);
            outv[pp * 2 + 1] = to_bf16(v0 * sn + v1 * cs);
        }
        const int kb = s >> 4, colk = s & 15;
        const int kc = o >> 2, quadk = o & 3;
        const size_t addr = ((((size_t)(n * 128 + kb) * 4 + kc) * 64) + quadk * 16 + colk) * 8;
        *(short8*)(Kp + addr) = outv;
    }
}

// ---------------------------------------------------------------------------
// MFMA flash attention v14 — L1-paired waves + in-block split-K=2.
//
// R9 post-mortem: per-CU KV delivery is pinned at ~23 B/cyc (v8 19, v11 23,
// v13 18 with broken schedule) — a per-CU vector-memory fill-BW wall. More
// waves can't raise it (v13); only fewer MISS BYTES per CU can. v14: 4-wave
// blocks over a 64-row x 2048-key tile. Wave w: rows row0+(w&1)*32, keys
// (w>>1)*1024... Waves (0,1) walk IDENTICAL key-step sequences (same
// addresses) -> the trailing wave's loads hit L1 (32 KB = 2-step window;
// raw s_barrier each iter keeps pairs in lockstep, no counter drain).
// Per-CU miss bytes halve (48 KB vs 96 KB per step-round); total L2 reads
// 786 -> 384 MB. Per-wave loop byte-for-byte = v11 (32 steps, ping-pong
// prefetch, 512 KB). Waves (0,2)/(1,3) combine key-halves via LDS, ONE
// barrier. 384 blocks x 4 waves = 6 waves/CU (= v11). launch_bounds(256,1)
// gives the allocator v8/v11-style freedom (R8 lesson: never clamp below
// the live set).
// ---------------------------------------------------------------------------
__global__ __launch_bounds__(256, 1)
void attn_mfma14(const short* __restrict__ Q, const short* __restrict__ Kp,
                 const short* __restrict__ Vp, short* __restrict__ O,
                 const int* __restrict__ seq_lens)
{
    __shared__ __attribute__((aligned(16))) short psw[4 * 1280];   // P transpose, per wave
    __shared__ __attribute__((aligned(16))) float sacc0[32 * 132]; // combine rows 0-31
    __shared__ __attribute__((aligned(16))) float sacc1[32 * 132]; // combine rows 32-63
    __shared__ float sl0[32], sl1[32];

    const int tid  = threadIdx.x;
    const int wave = tid >> 6;
    const int lane = tid & 63;
    const int quad = lane >> 4, col = lane & 15;
    const int rowh = wave & 1;           // row half within the 64-row tile
    const int keyh = wave >> 1;          // key half (0: 0..1023, 1: 1024..2047)

    // XCD-clustering swizzle: 384 blocks -> 8 chunks of 48 (1.5 heads of
    // K/V per XCD L2). Bijective since 384 % 8 == 0.
    const int orig = blockIdx.y * 32 + blockIdx.x;
    const int work = (orig & 7) * 48 + (orig >> 3);
    const int head = work >> 5;
    const int row0 = (work & 31) * 64 + rowh * 32;
    const int slen = seq_lens[0];

    // Q fragments: 2 row-tiles x 4 k-chunks.
    short8 qf[2][4];
    #pragma unroll
    for (int T = 0; T < 2; ++T)
        #pragma unroll
        for (int kc = 0; kc < 4; ++kc)
            qf[T][kc] = *(const short8*)(Q + (size_t)(row0 + T * 16 + col) * DIMN
                                         + head * HDIM + kc * 32 + quad * 8);

    f32x4 oacc[2][8];
    #pragma unroll
    for (int T = 0; T < 2; ++T)
        #pragma unroll
        for (int dt = 0; dt < 8; ++dt)
            #pragma unroll
            for (int r = 0; r < 4; ++r) oacc[T][dt][r] = 0.f;
    float lsum[2][4];
    #pragma unroll
    for (int T = 0; T < 2; ++T)
        #pragma unroll
        for (int r = 0; r < 4; ++r) lsum[T][r] = 0.f;

    const short* kbase = Kp + (size_t)head * 262144 + lane * 8;
    const short* vbase = Vp + (size_t)head * 262144 + lane * 8;
    short* pswm = psw + wave * 1280;
    const int step0 = keyh * 32;

    auto loadKV = [&](short8 (&kf)[8], short8 (&vf)[8], int step) {
        const short* ks = kbase + (size_t)step * 4096;
        const short* vs = vbase + (size_t)step * 4096;
        #pragma unroll
        for (int c = 0; c < 8; ++c) kf[c] = *(const short8*)(ks + c * 512);
        #pragma unroll
        for (int c = 0; c < 8; ++c) vf[c] = *(const short8*)(vs + c * 512);
    };

    auto compute = [&](short8 (&kf)[8], short8 (&vf)[8], int step) {
        // ---- S = Q K^T: 2 row-tiles x 32 keys ----
        f32x4 s[2][2];
        #pragma unroll
        for (int T = 0; T < 2; ++T)
            #pragma unroll
            for (int nt = 0; nt < 2; ++nt)
                #pragma unroll
                for (int r = 0; r < 4; ++r) s[T][nt][r] = 0.f;

        #pragma unroll
        for (int kc = 0; kc < 4; ++kc)
            #pragma unroll
            for (int T = 0; T < 2; ++T) {
                s[T][0] = __builtin_amdgcn_mfma_f32_16x16x32_bf16(qf[T][kc], kf[kc],     s[T][0], 0, 0, 0);
                s[T][1] = __builtin_amdgcn_mfma_f32_16x16x32_bf16(qf[T][kc], kf[4 + kc], s[T][1], 0, 0, 0);
            }

        // ---- mask + exp (max-free) + l accum + P transpose via tiny LDS ----
        const int kt0 = step * 32;
        #pragma unroll
        for (int T = 0; T < 2; ++T)
            #pragma unroll
            for (int nt = 0; nt < 2; ++nt) {
                const bool masked = (kt0 + nt * 16 + col >= slen);
                #pragma unroll
                for (int r = 0; r < 4; ++r) {
                    float p = masked ? 0.f : __expf(s[T][nt][r]);
                    lsum[T][r] += p;
                    pswm[T * 640 + (quad * 4 + r) * 40 + nt * 16 + col] = to_bf16(p);
                }
            }

        short8 pf0 = *(const short8*)&pswm[col * 40 + quad * 8];
        short8 pf1 = *(const short8*)&pswm[640 + col * 40 + quad * 8];

        // ---- PV: 8 d-tiles x 2 row-tiles ----
        #pragma unroll
        for (int dt = 0; dt < 8; ++dt) {
            oacc[0][dt] = __builtin_amdgcn_mfma_f32_16x16x32_bf16(pf0, vf[dt], oacc[0][dt], 0, 0, 0);
            oacc[1][dt] = __builtin_amdgcn_mfma_f32_16x16x32_bf16(pf1, vf[dt], oacc[1][dt], 0, 0, 0);
        }
    };

    short8 kA[8], vA[8], kB[8], vB[8];
    loadKV(kA, vA, step0);

    #pragma unroll 1
    for (int kt = 0; kt < 32; kt += 2) {
        loadKV(kB, vB, step0 + kt + 1);   // full next-step cluster BEFORE compute
        compute(kA, vA, step0 + kt);
        loadKV(kA, vA, step0 + kt + 2);   // last iter reads one step past this
                                          // wave's range (next key-half / next
                                          // head; head 11 keyh 1 reads into the
                                          // ob region -- allocated, value unused)
        compute(kB, vB, step0 + kt + 1);
        // Re-sync the L1-sharing pairs (0,1) and (2,3) every 2 steps so the
        // trailing wave's reads stay inside the 32 KB / 2-step L1 window.
        // Raw s_barrier: no vmcnt/lgkmcnt drain, in-flight prefetch preserved.
        __builtin_amdgcn_s_barrier();
    }

    // ---- reduce l over the 16 key-columns (within 16-lane groups) ----
    #pragma unroll
    for (int T = 0; T < 2; ++T)
        #pragma unroll
        for (int r = 0; r < 4; ++r) {
            #pragma unroll
            for (int off = 8; off; off >>= 1)
                lsum[T][r] += __shfl_xor(lsum[T][r], off, 64);
        }

    // ---- combine key-halves: pairs (0,2) rows 0-31, (1,3) rows 32-63 ----
    auto dump = [&](float* sa, float* sls) {
        #pragma unroll
        for (int T = 0; T < 2; ++T) {
            #pragma unroll
            for (int dt = 0; dt < 8; ++dt)
                #pragma unroll
                for (int r = 0; r < 4; ++r)
                    sa[(T * 16 + quad * 4 + r) * 132 + dt * 16 + col] = oacc[T][dt][r];
            if (col == 0) {
                #pragma unroll
                for (int r = 0; r < 4; ++r) sls[T * 16 + quad * 4 + r] = lsum[T][r];
            }
        }
    };

    if (wave == 2) dump(sacc0, sl0);
    if (wave == 3) dump(sacc1, sl1);
    __syncthreads();
    if (wave < 2) {
        const float* sa  = (wave == 0) ? sacc0 : sacc1;
        const float* sls = (wave == 0) ? sl0 : sl1;
        #pragma unroll
        for (int T = 0; T < 2; ++T) {
            float inv[4];
            #pragma unroll
            for (int r = 0; r < 4; ++r)
                inv[r] = 1.0f / (lsum[T][r] + sls[T * 16 + quad * 4 + r]);
            #pragma unroll
            for (int dt = 0; dt < 8; ++dt)
                #pragma unroll
                for (int r = 0; r < 4; ++r) {
                    const float o = oacc[T][dt][r]
                                  + sa[(T * 16 + quad * 4 + r) * 132 + dt * 16 + col];
                    O[(size_t)(row0 + T * 16 + quad * 4 + r) * DIMN
                      + head * HDIM + dt * 16 + col] = to_bf16(o * inv[r]);
                }
        }
    }
}

// ---------------------------------------------------------------------------
extern "C" void kernel_launch(void* const* d_in, const int* in_sizes, int n_in,
                              void* d_out, int out_size, void* d_ws, size_t ws_size,
                              hipStream_t stream)
{
    const float* x     = (const float*)d_in[0];
    const float* freqs = (const float*)d_in[1];
    const float* wq    = (const float*)d_in[2];
    const float* bq    = (const float*)d_in[3];
    const float* wk    = (const float*)d_in[4];
    const float* bk    = (const float*)d_in[5];
    const float* wv    = (const float*)d_in[6];
    const float* bv    = (const float*)d_in[7];
    const float* wo    = (const float*)d_in[8];
    const float* bo    = (const float*)d_in[9];
    const float* gq    = (const float*)d_in[10];
    const float* gk    = (const float*)d_in[11];
    const int* seq_lens   = (const int*)d_in[12];
    const int* grid_sizes = (const int*)d_in[13];
    float* out = (float*)d_out;

    const size_t NX = (size_t)SLEN * DIMN;
    const size_t NW = (size_t)DIMN * DIMN;
    short* xb  = (short*)d_ws;
    short* wqb = xb + NX;
    short* wkb = wqb + NW;
    short* wvb = wkb + NW;
    short* wob = wvb + NW;
    short* qb  = wob + NW;
    short* kb  = qb + NX;
    short* vp  = kb + NX;
    short* kp  = vp + NX;
    short* ob  = kp + NX;

    cast5<<<dim3(1536, 5), 256, 0, stream>>>(x, wq, wk, wv, wo,
                                             xb, wqb, wkb, wvb, wob,
                                             (int)NX, (int)NW);

    gemm_qkv<<<dim3(3 * DIMN / 128, SLEN / 64), 256, 0, stream>>>(
        xb, wqb, wkb, wvb, bq, bk, bv, qb, kb, vp);

    rms_rope_qk<<<dim3(SLEN, 2), 256, 0, stream>>>(qb, kb, kp, gq, gk, freqs, grid_sizes);

    attn_mfma14<<<dim3(32, NHEAD), 256, 0, stream>>>(qb, kp, vp, ob, seq_lens);

    gemm_out<<<dim3(DIMN / 128, SLEN / 64), 256, 0, stream>>>(ob, wob, bo, out);
}

// Round 11
// 234.362 us; speedup vs baseline: 1.0728x; 1.0728x over previous
//
#include <hip/hip_runtime.h>
#include <math.h>

#define DIMN 1536
#define NHEAD 12
#define HDIM 128
#define SLEN 2048
#define EPSV 1e-6f

typedef __attribute__((ext_vector_type(8))) short short8;
typedef __attribute__((ext_vector_type(4))) short short4v;
typedef __attribute__((ext_vector_type(4))) float f32x4;

typedef __attribute__((address_space(1))) const void gvoid_t;
typedef __attribute__((address_space(3))) void lvoid_t;

__device__ __forceinline__ void gload_lds16(const void* g, void* l) {
    __builtin_amdgcn_global_load_lds((gvoid_t*)g, (lvoid_t*)l, 16, 0, 0);
}

__device__ inline short to_bf16(float f) {
    union { float f; unsigned u; } v; v.f = f;
    unsigned r = (v.u + 0x7FFFu + ((v.u >> 16) & 1u)) >> 16;
    return (short)r;
}
__device__ inline float bf_to_f(short h) {
    union { unsigned u; float f; } v;
    v.u = ((unsigned)(unsigned short)h) << 16;
    return v.f;
}

// 8-chunk XOR swizzle for the GEMM LDS tiles.
__device__ __forceinline__ int swz8(int row, int c) {
    return c ^ (row & 7);
}

// ---------------------------------------------------------------------------
// Cast 5 fp32 tensors to bf16 (x + 4 weights), one launch.
// ---------------------------------------------------------------------------
__global__ __launch_bounds__(256)
void cast5(const float* s0, const float* s1, const float* s2,
           const float* s3, const float* s4,
           short* d0, short* d1, short* d2, short* d3, short* d4,
           int n0, int nw)
{
    const float* s; short* d; int n;
    switch (blockIdx.y) {
        case 0: s = s0; d = d0; n = n0; break;
        case 1: s = s1; d = d1; n = nw; break;
        case 2: s = s2; d = d2; n = nw; break;
        case 3: s = s3; d = d3; n = nw; break;
        default: s = s4; d = d4; n = nw; break;
    }
    int idx = (blockIdx.x * 256 + threadIdx.x) * 8;
    if (idx >= n) return;
    float4 a = *(const float4*)(s + idx);
    float4 b = *(const float4*)(s + idx + 4);
    short8 r;
    r[0] = to_bf16(a.x); r[1] = to_bf16(a.y); r[2] = to_bf16(a.z); r[3] = to_bf16(a.w);
    r[4] = to_bf16(b.x); r[5] = to_bf16(b.y); r[6] = to_bf16(b.z); r[7] = to_bf16(b.w);
    *(short8*)(d + idx) = r;
}

// ---------------------------------------------------------------------------
// BM=64 x BN=128 x BK=64 MFMA GEMM core, two-barrier single-buffer.
// (R7 structure — grid-balanced, cross-block TLP hides staging.)
// ---------------------------------------------------------------------------
__device__ __forceinline__ void gemm_mainloop(const short* __restrict__ A,
    const short* __restrict__ W, int m0, int n0, int K,
    short* As, short* Bs, f32x4 (&acc)[2][4])
{
    const int tid = threadIdx.x;
    const int wave = tid >> 6, lane = tid & 63;
    const int quad = lane >> 4, col = lane & 15;
    const int wm = wave >> 1, wn = wave & 1;
    const int sr = tid >> 3;     // 0..31
    const int sc = tid & 7;

    for (int kt = 0; kt < K; kt += 64) {
        __syncthreads();
        #pragma unroll
        for (int i = 0; i < 2; ++i) {
            const int row = i * 32 + sr;
            const int c = swz8(row, sc);
            gload_lds16(A + (size_t)(m0 + row) * K + kt + c * 8, As + i * 2048 + tid * 8);
        }
        #pragma unroll
        for (int i = 0; i < 4; ++i) {
            const int row = i * 32 + sr;
            const int c = swz8(row, sc);
            gload_lds16(W + (size_t)(n0 + row) * K + kt + c * 8, Bs + i * 2048 + tid * 8);
        }
        __syncthreads();

        #pragma unroll
        for (int kb = 0; kb < 2; ++kb) {
            short8 af[2], bf[4];
            #pragma unroll
            for (int mt = 0; mt < 2; ++mt) {
                const int row = wm * 32 + mt * 16 + col;
                af[mt] = *(const short8*)&As[row * 64 + swz8(row, kb * 4 + quad) * 8];
            }
            #pragma unroll
            for (int nt = 0; nt < 4; ++nt) {
                const int row = wn * 64 + nt * 16 + col;
                bf[nt] = *(const short8*)&Bs[row * 64 + swz8(row, kb * 4 + quad) * 8];
            }
            #pragma unroll
            for (int mt = 0; mt < 2; ++mt)
                #pragma unroll
                for (int nt = 0; nt < 4; ++nt)
                    acc[mt][nt] = __builtin_amdgcn_mfma_f32_16x16x32_bf16(
                        af[mt], bf[nt], acc[mt][nt], 0, 0, 0);
        }
    }
}

// ---------------------------------------------------------------------------
// Fused QKV GEMM, 64x128 tiles; sel==2 (V) writes fragment-swizzled Vp.
// Vp chunks are 32-key-step-major: chunk = (head*64 + step)*8 + dt; each
// step's V tile is 8 KB contiguous and fragment-ready for attn.
// ---------------------------------------------------------------------------
__global__ __launch_bounds__(256)
void gemm_qkv(const short* __restrict__ A,
              const short* __restrict__ W0, const short* __restrict__ W1,
              const short* __restrict__ W2,
              const float* __restrict__ b0, const float* __restrict__ b1,
              const float* __restrict__ b2,
              short* __restrict__ Y0, short* __restrict__ Y1,
              short* __restrict__ Vp)
{
    __shared__ __attribute__((aligned(16))) short As[64 * 64];
    __shared__ __attribute__((aligned(16))) short Bs[128 * 64];

    const int sel = blockIdx.x / (DIMN / 128);
    const int nb  = blockIdx.x % (DIMN / 128);
    const short* W    = (sel == 0) ? W0 : (sel == 1) ? W1 : W2;
    const float* bias = (sel == 0) ? b0 : (sel == 1) ? b1 : b2;

    const int tid = threadIdx.x;
    const int wave = tid >> 6, lane = tid & 63;
    const int quad = lane >> 4, col = lane & 15;
    const int wm = wave >> 1, wn = wave & 1;
    const int m0 = blockIdx.y * 64, n0 = nb * 128;

    f32x4 acc[2][4];
    #pragma unroll
    for (int i = 0; i < 2; ++i)
        #pragma unroll
        for (int j = 0; j < 4; ++j)
            #pragma unroll
            for (int r = 0; r < 4; ++r) acc[i][j][r] = 0.f;

    gemm_mainloop(A, W, m0, n0, DIMN, As, Bs, acc);

    if (sel < 2) {
        short* Y = (sel == 0) ? Y0 : Y1;
        #pragma unroll
        for (int mt = 0; mt < 2; ++mt) {
            #pragma unroll
            for (int nt = 0; nt < 4; ++nt) {
                const int n = n0 + wn * 64 + nt * 16 + col;
                const float bb = bias[n];
                #pragma unroll
                for (int r = 0; r < 4; ++r) {
                    const int m = m0 + wm * 32 + mt * 16 + quad * 4 + r;
                    Y[(size_t)m * DIMN + n] = to_bf16(acc[mt][nt][r] + bb);
                }
            }
        }
    } else {
        const int head = nb;
        const int step = blockIdx.y * 2 + wm;      // 32-key step index
        #pragma unroll
        for (int mt = 0; mt < 2; ++mt) {
            #pragma unroll
            for (int nt = 0; nt < 4; ++nt) {
                const int n = n0 + wn * 64 + nt * 16 + col;
                const float bb = bias[n];
                const int dt = wn * 4 + nt;
                const int chunk = (head * 64 + step) * 8 + dt;
                const int off = (mt * 2 + (quad >> 1)) * 128 + col * 8 + (quad & 1) * 4;
                short4v o;
                #pragma unroll
                for (int r = 0; r < 4; ++r) o[r] = to_bf16(acc[mt][nt][r] + bb);
                *(short4v*)(Vp + (size_t)chunk * 512 + off) = o;
            }
        }
    }
}

// ---------------------------------------------------------------------------
// Output-projection GEMM, 64x96 tiles, fp32 out.
//
// R10 rebalance: the 64x128 version had 384 blocks = 1.5 blocks/CU -- the
// same tail pathology measured in R6 (half the CUs idle in round 2). 64x96
// gives grid (16,32) = 512 blocks = 2.0/CU exact. LDS 20 KB; staging adds a
// third 32-row round for B; waves 2x2 over (64,96), acc[2][3] per wave.
// ---------------------------------------------------------------------------
__global__ __launch_bounds__(256)
void gemm_out(const short* __restrict__ A, const short* __restrict__ W,
              const float* __restrict__ bias, float* __restrict__ Yf)
{
    __shared__ __attribute__((aligned(16))) short As[64 * 64];
    __shared__ __attribute__((aligned(16))) short Bs[96 * 64];

    const int tid = threadIdx.x;
    const int wave = tid >> 6, lane = tid & 63;
    const int quad = lane >> 4, col = lane & 15;
    const int wm = wave >> 1, wn = wave & 1;
    const int m0 = blockIdx.y * 64, n0 = blockIdx.x * 96;
    const int sr = tid >> 3;
    const int sc = tid & 7;

    f32x4 acc[2][3];
    #pragma unroll
    for (int i = 0; i < 2; ++i)
        #pragma unroll
        for (int j = 0; j < 3; ++j)
            #pragma unroll
            for (int r = 0; r < 4; ++r) acc[i][j][r] = 0.f;

    for (int kt = 0; kt < DIMN; kt += 64) {
        __syncthreads();
        #pragma unroll
        for (int i = 0; i < 2; ++i) {
            const int row = i * 32 + sr;
            const int c = swz8(row, sc);
            gload_lds16(A + (size_t)(m0 + row) * DIMN + kt + c * 8, As + i * 2048 + tid * 8);
        }
        #pragma unroll
        for (int i = 0; i < 3; ++i) {
            const int row = i * 32 + sr;
            const int c = swz8(row, sc);
            gload_lds16(W + (size_t)(n0 + row) * DIMN + kt + c * 8, Bs + i * 2048 + tid * 8);
        }
        __syncthreads();

        #pragma unroll
        for (int kb = 0; kb < 2; ++kb) {
            short8 af[2], bf[3];
            #pragma unroll
            for (int mt = 0; mt < 2; ++mt) {
                const int row = wm * 32 + mt * 16 + col;
                af[mt] = *(const short8*)&As[row * 64 + swz8(row, kb * 4 + quad) * 8];
            }
            #pragma unroll
            for (int nt = 0; nt < 3; ++nt) {
                const int row = wn * 48 + nt * 16 + col;
                bf[nt] = *(const short8*)&Bs[row * 64 + swz8(row, kb * 4 + quad) * 8];
            }
            #pragma unroll
            for (int mt = 0; mt < 2; ++mt)
                #pragma unroll
                for (int nt = 0; nt < 3; ++nt)
                    acc[mt][nt] = __builtin_amdgcn_mfma_f32_16x16x32_bf16(
                        af[mt], bf[nt], acc[mt][nt], 0, 0, 0);
        }
    }

    #pragma unroll
    for (int mt = 0; mt < 2; ++mt) {
        #pragma unroll
        for (int nt = 0; nt < 3; ++nt) {
            const int n = n0 + wn * 48 + nt * 16 + col;
            const float bb = bias[n];
            #pragma unroll
            for (int r = 0; r < 4; ++r) {
                const int m = m0 + wm * 32 + mt * 16 + quad * 4 + r;
                Yf[(size_t)m * DIMN + n] = acc[mt][nt][r] + bb;
            }
        }
    }
}

// ---------------------------------------------------------------------------
// Fused RMSNorm + RoPE for Q (grid.y==0, in-place) and K->Kp (grid.y==1).
// ---------------------------------------------------------------------------
__global__ __launch_bounds__(256)
void rms_rope_qk(short* __restrict__ qbuf, const short* __restrict__ kbuf,
                 short* __restrict__ Kp,
                 const float* __restrict__ gq, const float* __restrict__ gk,
                 const float* __restrict__ freqs, const int* __restrict__ grid_sizes)
{
    const int s = blockIdx.x;
    const int isK = blockIdx.y;
    const int tid = threadIdx.x;
    short* qrow = qbuf + (size_t)s * DIMN;
    const short* row = isK ? (kbuf + (size_t)s * DIMN) : qrow;
    const float* g = isK ? gk : gq;

    float ss = 0.f;
    if (tid < 192) {
        short8 v = *(const short8*)(row + tid * 8);
        #pragma unroll
        for (int j = 0; j < 8; ++j) { float f = bf_to_f(v[j]); ss += f * f; }
    }
    #pragma unroll
    for (int off = 32; off; off >>= 1) ss += __shfl_down(ss, off, 64);

    __shared__ float red[4];
    __shared__ float s_scale;
    if ((tid & 63) == 0) red[tid >> 6] = ss;
    __syncthreads();
    if (tid == 0) {
        float t = red[0] + red[1] + red[2] + red[3];
        float sc = rsqrtf(t / (float)DIMN + EPSV);
        s_scale = isK ? sc : sc * 0.08838834764831845f;
    }
    __syncthreads();
    const float scale = s_scale;

    const int h = grid_sizes[1], w = grid_sizes[2];
    const int fi = s / (h * w);
    const int hi = (s / w) % h;
    const int wi = s % w;

    if (!isK) {
        for (int p = tid; p < NHEAD * 64; p += 256) {
            const int n = p >> 6;
            const int d = p & 63;
            const int idx = (d < 22) ? fi : ((d < 43) ? hi : wi);
            const float ang = freqs[idx * 64 + d];
            float sn, cs;
            __sincosf(ang, &sn, &cs);
            const int base = n * HDIM + 2 * d;
            const float v0 = bf_to_f(qrow[base]) * scale * g[base];
            const float v1 = bf_to_f(qrow[base + 1]) * scale * g[base + 1];
            qrow[base]     = to_bf16(v0 * cs - v1 * sn);
            qrow[base + 1] = to_bf16(v0 * sn + v1 * cs);
        }
    } else if (tid < 192) {
        const int n = tid >> 4;
        const int o = tid & 15;
        short8 outv;
        #pragma unroll
        for (int pp = 0; pp < 4; ++pp) {
            const int pd = o * 4 + pp;
            const int idx = (pd < 22) ? fi : ((pd < 43) ? hi : wi);
            const float ang = freqs[idx * 64 + pd];
            float sn, cs;
            __sincosf(ang, &sn, &cs);
            const int base = n * HDIM + 2 * pd;
            const float v0 = bf_to_f(row[base]) * scale * g[base];
            const float v1 = bf_to_f(row[base + 1]) * scale * g[base + 1];
            outv[pp * 2]     = to_bf16(v0 * cs - v1 * sn);
            outv[pp * 2 + 1] = to_bf16(v0 * sn + v1 * cs);
        }
        const int kb = s >> 4, colk = s & 15;
        const int kc = o >> 2, quadk = o & 3;
        const size_t addr = ((((size_t)(n * 128 + kb) * 4 + kc) * 64) + quadk * 16 + colk) * 8;
        *(short8*)(Kp + addr) = outv;
    }
}

// ---------------------------------------------------------------------------
// MFMA flash attention v11 — v8 prefetch structure + in-block split-K.
// REVERTED VERBATIM from R7 (proven 56 us). Five structural variants
// (v9 split-K no-prefetch, v12 clamp-spill, v13 split-K4, v14 L1-pair)
// all failed to beat it; v11 sits at the per-CU KV-delivery equilibrium
// (~23 B/cyc) for this decomposition.
// ---------------------------------------------------------------------------
__global__ __launch_bounds__(128)
void attn_mfma11(const short* __restrict__ Q, const short* __restrict__ Kp,
                 const short* __restrict__ Vp, short* __restrict__ O,
                 const int* __restrict__ seq_lens)
{
    __shared__ __attribute__((aligned(16))) short psw[2 * 1280]; // P transpose, per wave
    __shared__ __attribute__((aligned(16))) float sacc[32 * 132]; // combine: 32 rows x 128d
    __shared__ float sl[32];                                      // combine: row sums

    const int tid  = threadIdx.x;
    const int wave = tid >> 6;           // 0: keys 0..1023, 1: keys 1024..2047
    const int lane = tid & 63;
    const int quad = lane >> 4, col = lane & 15;

    // XCD-clustering swizzle: 768 blocks -> 8 chunks of 96 (1.5 heads of
    // K/V ~ 1.5 MB per XCD L2). Bijective since 768 % 8 == 0.
    const int orig = blockIdx.y * 64 + blockIdx.x;
    const int work = (orig & 7) * 96 + (orig >> 3);
    const int head = work >> 6;
    const int row0 = (work & 63) * 32;
    const int slen = seq_lens[0];

    // Q fragments: 2 row-tiles x 4 k-chunks.
    short8 qf[2][4];
    #pragma unroll
    for (int T = 0; T < 2; ++T)
        #pragma unroll
        for (int kc = 0; kc < 4; ++kc)
            qf[T][kc] = *(const short8*)(Q + (size_t)(row0 + T * 16 + col) * DIMN
                                         + head * HDIM + kc * 32 + quad * 8);

    f32x4 oacc[2][8];
    #pragma unroll
    for (int T = 0; T < 2; ++T)
        #pragma unroll
        for (int dt = 0; dt < 8; ++dt)
            #pragma unroll
            for (int r = 0; r < 4; ++r) oacc[T][dt][r] = 0.f;
    float lsum[2][4];
    #pragma unroll
    for (int T = 0; T < 2; ++T)
        #pragma unroll
        for (int r = 0; r < 4; ++r) lsum[T][r] = 0.f;

    const short* kbase = Kp + (size_t)head * 262144 + lane * 8;
    const short* vbase = Vp + (size_t)head * 262144 + lane * 8;
    short* pswm = psw + wave * 1280;
    const int step0 = wave * 32;

    auto loadKV = [&](short8 (&kf)[8], short8 (&vf)[8], int step) {
        const short* ks = kbase + (size_t)step * 4096;
        const short* vs = vbase + (size_t)step * 4096;
        #pragma unroll
        for (int c = 0; c < 8; ++c) kf[c] = *(const short8*)(ks + c * 512);
        #pragma unroll
        for (int c = 0; c < 8; ++c) vf[c] = *(const short8*)(vs + c * 512);
    };

    auto compute = [&](short8 (&kf)[8], short8 (&vf)[8], int step) {
        // ---- S = Q K^T: 2 row-tiles x 32 keys ----
        f32x4 s[2][2];
        #pragma unroll
        for (int T = 0; T < 2; ++T)
            #pragma unroll
            for (int nt = 0; nt < 2; ++nt)
                #pragma unroll
                for (int r = 0; r < 4; ++r) s[T][nt][r] = 0.f;

        #pragma unroll
        for (int kc = 0; kc < 4; ++kc)
            #pragma unroll
            for (int T = 0; T < 2; ++T) {
                s[T][0] = __builtin_amdgcn_mfma_f32_16x16x32_bf16(qf[T][kc], kf[kc],     s[T][0], 0, 0, 0);
                s[T][1] = __builtin_amdgcn_mfma_f32_16x16x32_bf16(qf[T][kc], kf[4 + kc], s[T][1], 0, 0, 0);
            }

        // ---- mask + exp (max-free) + l accum + P transpose via tiny LDS ----
        const int kt0 = step * 32;
        #pragma unroll
        for (int T = 0; T < 2; ++T)
            #pragma unroll
            for (int nt = 0; nt < 2; ++nt) {
                const bool masked = (kt0 + nt * 16 + col >= slen);
                #pragma unroll
                for (int r = 0; r < 4; ++r) {
                    float p = masked ? 0.f : __expf(s[T][nt][r]);
                    lsum[T][r] += p;
                    pswm[T * 640 + (quad * 4 + r) * 40 + nt * 16 + col] = to_bf16(p);
                }
            }

        short8 pf0 = *(const short8*)&pswm[col * 40 + quad * 8];
        short8 pf1 = *(const short8*)&pswm[640 + col * 40 + quad * 8];

        // ---- PV: 8 d-tiles x 2 row-tiles ----
        #pragma unroll
        for (int dt = 0; dt < 8; ++dt) {
            oacc[0][dt] = __builtin_amdgcn_mfma_f32_16x16x32_bf16(pf0, vf[dt], oacc[0][dt], 0, 0, 0);
            oacc[1][dt] = __builtin_amdgcn_mfma_f32_16x16x32_bf16(pf1, vf[dt], oacc[1][dt], 0, 0, 0);
        }
    };

    short8 kA[8], vA[8], kB[8], vB[8];
    loadKV(kA, vA, step0);

    #pragma unroll 1
    for (int kt = 0; kt < 32; kt += 2) {
        loadKV(kB, vB, step0 + kt + 1);   // full next-step cluster BEFORE compute
        compute(kA, vA, step0 + kt);
        loadKV(kA, vA, step0 + kt + 2);   // last iter reads one step past this
                                          // wave's range (next head / ob region,
                                          // allocated; value unused)
        compute(kB, vB, step0 + kt + 1);
    }

    // ---- reduce l over the 16 key-columns (within 16-lane groups) ----
    #pragma unroll
    for (int T = 0; T < 2; ++T)
        #pragma unroll
        for (int r = 0; r < 4; ++r) {
            #pragma unroll
            for (int off = 8; off; off >>= 1)
                lsum[T][r] += __shfl_xor(lsum[T][r], off, 64);
        }

    // ---- combine the two key-halves through LDS ----
    if (wave == 1) {
        #pragma unroll
        for (int T = 0; T < 2; ++T) {
            #pragma unroll
            for (int dt = 0; dt < 8; ++dt)
                #pragma unroll
                for (int r = 0; r < 4; ++r)
                    sacc[(T * 16 + quad * 4 + r) * 132 + dt * 16 + col] = oacc[T][dt][r];
            if (col == 0) {
                #pragma unroll
                for (int r = 0; r < 4; ++r) sl[T * 16 + quad * 4 + r] = lsum[T][r];
            }
        }
    }
    __syncthreads();
    if (wave == 0) {
        #pragma unroll
        for (int T = 0; T < 2; ++T) {
            float inv[4];
            #pragma unroll
            for (int r = 0; r < 4; ++r)
                inv[r] = 1.0f / (lsum[T][r] + sl[T * 16 + quad * 4 + r]);
            #pragma unroll
            for (int dt = 0; dt < 8; ++dt)
                #pragma unroll
                for (int r = 0; r < 4; ++r) {
                    const float o = oacc[T][dt][r]
                                  + sacc[(T * 16 + quad * 4 + r) * 132 + dt * 16 + col];
                    O[(size_t)(row0 + T * 16 + quad * 4 + r) * DIMN
                      + head * HDIM + dt * 16 + col] = to_bf16(o * inv[r]);
                }
        }
    }
}

// ---------------------------------------------------------------------------
extern "C" void kernel_launch(void* const* d_in, const int* in_sizes, int n_in,
                              void* d_out, int out_size, void* d_ws, size_t ws_size,
                              hipStream_t stream)
{
    const float* x     = (const float*)d_in[0];
    const float* freqs = (const float*)d_in[1];
    const float* wq    = (const float*)d_in[2];
    const float* bq    = (const float*)d_in[3];
    const float* wk    = (const float*)d_in[4];
    const float* bk    = (const float*)d_in[5];
    const float* wv    = (const float*)d_in[6];
    const float* bv    = (const float*)d_in[7];
    const float* wo    = (const float*)d_in[8];
    const float* bo    = (const float*)d_in[9];
    const float* gq    = (const float*)d_in[10];
    const float* gk    = (const float*)d_in[11];
    const int* seq_lens   = (const int*)d_in[12];
    const int* grid_sizes = (const int*)d_in[13];
    float* out = (float*)d_out;

    const size_t NX = (size_t)SLEN * DIMN;
    const size_t NW = (size_t)DIMN * DIMN;
    short* xb  = (short*)d_ws;
    short* wqb = xb + NX;
    short* wkb = wqb + NW;
    short* wvb = wkb + NW;
    short* wob = wvb + NW;
    short* qb  = wob + NW;
    short* kb  = qb + NX;
    short* vp  = kb + NX;
    short* kp  = vp + NX;
    short* ob  = kp + NX;

    cast5<<<dim3(1536, 5), 256, 0, stream>>>(x, wq, wk, wv, wo,
                                             xb, wqb, wkb, wvb, wob,
                                             (int)NX, (int)NW);

    gemm_qkv<<<dim3(3 * DIMN / 128, SLEN / 64), 256, 0, stream>>>(
        xb, wqb, wkb, wvb, bq, bk, bv, qb, kb, vp);

    rms_rope_qk<<<dim3(SLEN, 2), 256, 0, stream>>>(qb, kb, kp, gq, gk, freqs, grid_sizes);

    attn_mfma11<<<dim3(64, NHEAD), 128, 0, stream>>>(qb, kp, vp, ob, seq_lens);

    gemm_out<<<dim3(DIMN / 96, SLEN / 64), 256, 0, stream>>>(ob, wob, bo, out);
}